// Round 10
// baseline (302.851 us; speedup 1.0000x reference)
//
#include <hip/hip_runtime.h>

#define N_NODES 50000
#define N_EDGES 800000
#define DIM 256
#define ACT 64
#define SCAN_B 256
#define SCAN_NB ((N_NODES + SCAN_B - 1) / SCAN_B)   // 196
#define SLICE_ELEMS ((size_t)N_NODES * 32)          // elems per 32-dim slice
#define AGG_CHUNKS 512
#define NPC ((N_NODES + AGG_CHUNKS - 1) / AGG_CHUNKS)  // 98 nodes per chunk
#define CSR_MAX (N_EDGES + 16 * N_NODES)            // padded-to-16 CSR upper bound

typedef __attribute__((ext_vector_type(8))) short short8_t;
typedef __attribute__((ext_vector_type(4))) float f32x4;
typedef __attribute__((ext_vector_type(4))) unsigned short ushort4_t;

__device__ __forceinline__ unsigned short f2b(float x) {   // f32 -> bf16 RNE
    unsigned u = __float_as_uint(x);
    unsigned r = u + 0x7FFFu + ((u >> 16) & 1u);
    return (unsigned short)(r >> 16);
}

// ---------------- dtype conversion ----------------

// x fp32 row-major -> bf16 SLICED [slice][node][32]
__global__ __launch_bounds__(256) void k_cvt_x(const float* __restrict__ x,
                                               unsigned short* __restrict__ xb) {
    int i = blockIdx.x * blockDim.x + threadIdx.x;   // one thread = 8 elems
    const int TOT = N_NODES * DIM / 8;
    if (i >= TOT) return;
    const float4* src = (const float4*)(x) + (size_t)i * 2;
    float4 a = src[0], b = src[1];
    int row = i >> 5;
    int col0 = (i << 3) & 255;
    int slice = col0 >> 5, within = col0 & 31;
    ushort4_t lo, hi;
    lo.x = f2b(a.x); lo.y = f2b(a.y); lo.z = f2b(a.z); lo.w = f2b(a.w);
    hi.x = f2b(b.x); hi.y = f2b(b.y); hi.z = f2b(b.z); hi.w = f2b(b.w);
    ushort4_t* dst = (ushort4_t*)(xb + (size_t)slice * SLICE_ELEMS + (size_t)row * 32 + within);
    dst[0] = lo; dst[1] = hi;
}

// transpose + convert both W1,W2 [k][n] fp32 -> Wt [n][k] bf16
__global__ __launch_bounds__(256) void k_cvt_wt2(const float* __restrict__ W1,
                                                 const float* __restrict__ W2,
                                                 unsigned short* __restrict__ W1t,
                                                 unsigned short* __restrict__ W2t) {
    int b = blockIdx.x;
    const float* W = (b < 256) ? W1 : W2;
    unsigned short* Wt = (b < 256) ? W1t : W2t;
    int i = (b & 255) * 256 + threadIdx.x;
    int k = i >> 8, n = i & 255;
    Wt[n * DIM + k] = f2b(W[k * DIM + n]);
}

// ---------------- degree (degi pre-zeroed; self-loop accounted as +1 in scan) ----------------

__global__ void k_deg_count(const int* __restrict__ ei, int* degi) {
    int e = blockIdx.x * blockDim.x + threadIdx.x;
    if (e < N_EDGES) atomicAdd(&degi[ei[N_EDGES + e]], 1);  // dst row
}

// ---------------- hierarchical exclusive scan over PADDED row lengths ----------------
// padded_len(i) = roundup16(degi[i] + 1); padding slots stay (src=0, norm=0.0).

__global__ __launch_bounds__(SCAN_B) void k_scan_local(const int* __restrict__ degi,
                                                       int* lexc, int* btot) {
    __shared__ int sm[SCAN_B];
    int t = threadIdx.x;
    int i = blockIdx.x * SCAN_B + t;
    int v = (i < N_NODES) ? ((degi[i] + 16) & ~15) : 0;   // roundup16(deg+1)
    sm[t] = v;
    __syncthreads();
#pragma unroll
    for (int off = 1; off < SCAN_B; off <<= 1) {
        int u = (t >= off) ? sm[t - off] : 0;
        __syncthreads();
        sm[t] += u;
        __syncthreads();
    }
    if (i < N_NODES) lexc[i] = sm[t] - v;
    if (t == SCAN_B - 1) btot[blockIdx.x] = sm[t];
}

__global__ __launch_bounds__(SCAN_B) void k_scan_tops(const int* __restrict__ btot,
                                                      int* bbase, int* rowstart) {
    __shared__ int sm[SCAN_B];
    int t = threadIdx.x;
    int v = (t < SCAN_NB) ? btot[t] : 0;
    sm[t] = v;
    __syncthreads();
#pragma unroll
    for (int off = 1; off < SCAN_B; off <<= 1) {
        int u = (t >= off) ? sm[t - off] : 0;
        __syncthreads();
        sm[t] += u;
        __syncthreads();
    }
    if (t < SCAN_NB) bbase[t] = sm[t] - v;
    if (t == SCAN_NB - 1) rowstart[N_NODES] = sm[t];
}

// NOTE: csr_pair.x stores src<<6 (byte offset of the 64B slice row) pre-shifted.
__global__ __launch_bounds__(SCAN_B) void k_scan_apply(const int* __restrict__ degi,
                                                       const int* __restrict__ lexc,
                                                       const int* __restrict__ bbase,
                                                       int* rowstart, int* fillpos,
                                                       float* dinv, int2* csr_pair) {
    int i = blockIdx.x * SCAN_B + threadIdx.x;
    if (i >= N_NODES) return;
    int rs = bbase[blockIdx.x] + lexc[i];
    rowstart[i] = rs;
    int d = degi[i] + 1;
    float di = rsqrtf((float)d);
    dinv[i] = di;
    int2 p; p.x = i << 6; p.y = __float_as_int(di * di);
    csr_pair[rs] = p;          // self-loop entry first in row
    fillpos[i] = rs + 1;
}

__global__ void k_fill_edge(const int* __restrict__ ei,
                            const float* __restrict__ dinv, int* fillpos,
                            int2* csr_pair) {
    int e = blockIdx.x * blockDim.x + threadIdx.x;
    if (e < N_EDGES) {
        int s = ei[e];
        int d = ei[N_EDGES + e];
        int p = atomicAdd(&fillpos[d], 1);
        int2 pr; pr.x = s << 6; pr.y = __float_as_int(dinv[s] * dinv[d]);
        csr_pair[p] = pr;
    }
}

// ---------------- bf16 MFMA GEMM: H = A @ Wt^T  (A, H in SLICED layout) ----------------

__global__ __launch_bounds__(256) void k_gemm_mfma(const unsigned short* __restrict__ A,
                                                   const unsigned short* __restrict__ Wt,
                                                   unsigned short* __restrict__ H,
                                                   int M) {
    __shared__ char lds[40960];          // As 64x64 bf16 (8KB) + Bs 256x64 bf16 (32KB)
    char* AsB = lds;
    char* BsB = lds + 8192;

    int tid = threadIdx.x;
    int w = tid >> 6;
    int l = tid & 63;
    int r0 = blockIdx.x * 64;

    f32x4 acc[4][4];
#pragma unroll
    for (int i = 0; i < 4; ++i)
#pragma unroll
        for (int j = 0; j < 4; ++j) acc[i][j] = (f32x4)(0.f);

    for (int kt = 0; kt < 4; ++kt) {
        int k0 = kt * 64;
#pragma unroll
        for (int i = 0; i < 2; ++i) {
            int c = tid + i * 256;
            int row = c >> 3, kc = c & 7;
            int k = k0 + kc * 8;
            int slice = k >> 5, within = k & 31;
            int g = r0 + row; if (g >= M) g = M - 1;
            short8_t v = *(const short8_t*)(A + (size_t)slice * SLICE_ELEMS + (size_t)g * 32 + within);
            int off = (row * 128 + kc * 16) ^ ((row & 7) << 4);
            *(short8_t*)(AsB + off) = v;
        }
#pragma unroll
        for (int i = 0; i < 8; ++i) {
            int c = tid + i * 256;
            int n = c >> 3, kc = c & 7;
            short8_t v = *(const short8_t*)(Wt + n * DIM + k0 + kc * 8);
            int off = (n * 128 + kc * 16) ^ ((n & 7) << 4);
            *(short8_t*)(BsB + off) = v;
        }
        __syncthreads();

#pragma unroll
        for (int kf = 0; kf < 2; ++kf) {
            int kb = kf * 64 + (l >> 4) * 16;
            short8_t a[4], b[4];
#pragma unroll
            for (int fm = 0; fm < 4; ++fm) {
                int ra = fm * 16 + (l & 15);
                a[fm] = *(const short8_t*)(AsB + ((ra * 128 + kb) ^ ((ra & 7) << 4)));
            }
#pragma unroll
            for (int fn = 0; fn < 4; ++fn) {
                int nb = w * 64 + fn * 16 + (l & 15);
                b[fn] = *(const short8_t*)(BsB + ((nb * 128 + kb) ^ ((nb & 7) << 4)));
            }
#pragma unroll
            for (int fm = 0; fm < 4; ++fm)
#pragma unroll
                for (int fn = 0; fn < 4; ++fn)
                    acc[fm][fn] = __builtin_amdgcn_mfma_f32_16x16x32_bf16(
                        a[fm], b[fn], acc[fm][fn], 0, 0, 0);
        }
        __syncthreads();
    }

    // C/D layout: col = l&15, row = (l>>4)*4 + i ; write SLICED
#pragma unroll
    for (int fm = 0; fm < 4; ++fm) {
#pragma unroll
        for (int i = 0; i < 4; ++i) {
            int row = r0 + fm * 16 + ((l >> 4) << 2) + i;
            if (row >= M) continue;
#pragma unroll
            for (int fn = 0; fn < 4; ++fn) {
                int col = w * 64 + fn * 16 + (l & 15);
                int slice = col >> 5;
                H[(size_t)slice * SLICE_ELEMS + (size_t)row * 32 + (col & 31)] = f2b(acc[fm][fn][i]);
            }
        }
    }
}

// ---------------- sliced aggregation v4: 8-lane group/node, 16 slots/round, dbuf ------
// Per 16-slot round: one int4 coalesced pair load per lane (2 pairs x 8 lanes =
// 16 pairs), prefetched one round ahead; one ds_write_b128 into the double-
// buffered group slot; then 16 x { ds_read_b64 (broadcast, conflict-free) ->
// independent 64B gather -> 4 fma }. 16 gathers in flight per group = 2x R5's
// MLP at R5's register/LDS budget. Rows padded to x16 (padding: src=0, norm=0
// -> row0 * 0). Group is sub-wave: LDS is wave-synchronous, no barrier.

__global__ __launch_bounds__(256) void k_agg_sliced(const unsigned short* __restrict__ H,
                                                    const int* __restrict__ rowstart,
                                                    const int2* __restrict__ csr_pair,
                                                    const float* __restrict__ bias,
                                                    unsigned short* __restrict__ X,
                                                    float* __restrict__ gsum,
                                                    int write_out) {
    __shared__ long long pbuf[32][2][17];   // 32 groups x dbuf x (16+1 pad)
    int slice = blockIdx.x & 7;
    int chunk = blockIdx.x >> 3;
    int g = threadIdx.x >> 3;        // 32 groups of 8 lanes
    int lane = threadIdx.x & 7;
    const char* Hb = (const char*)(H + (size_t)slice * SLICE_ELEMS) + (lane << 3);
    unsigned short* Xs = X + (size_t)slice * SLICE_ELEMS;
    int d0 = slice * 32 + lane * 4;
    float4 bb = *(const float4*)&bias[d0];
    float c0 = 0.f, c1 = 0.f, c2 = 0.f, c3 = 0.f;
    int nEnd = (chunk + 1) * NPC; if (nEnd > N_NODES) nEnd = N_NODES;
    for (int n = chunk * NPC + g; n < nEnd; n += 32) {
        int beg = rowstart[n], end = rowstart[n + 1];   // length multiple of 16
        float a0 = 0.f, a1 = 0.f, a2 = 0.f, a3 = 0.f;
        int4 u = *(const int4*)(csr_pair + beg + lane * 2);
        int r = 0;
        for (int e = beg; e < end; e += 16, ++r) {
            int enext = (e + 16 < end) ? e + 16 : e;
            int4 un = *(const int4*)(csr_pair + enext + lane * 2);
            long long* pb = &pbuf[g][r & 1][0];
            *(int4*)(pb + lane * 2) = u;
#pragma unroll
            for (int i = 0; i < 16; ++i) {
                long long pv = pb[i];
                unsigned off = (unsigned)(int)pv;               // src<<6 pre-shifted
                float nm = __int_as_float((int)(pv >> 32));
                uint2 q = *(const uint2*)(Hb + off);            // 64B/group, independent
                a0 = fmaf(nm, __uint_as_float(q.x << 16), a0);
                a1 = fmaf(nm, __uint_as_float(q.x & 0xFFFF0000u), a1);
                a2 = fmaf(nm, __uint_as_float(q.y << 16), a2);
                a3 = fmaf(nm, __uint_as_float(q.y & 0xFFFF0000u), a3);
            }
            u = un;
        }
        float o0 = fmaxf(a0 + bb.x, 0.f);
        float o1 = fmaxf(a1 + bb.y, 0.f);
        float o2 = fmaxf(a2 + bb.z, 0.f);
        float o3 = fmaxf(a3 + bb.w, 0.f);
        if (write_out) {
            ushort4_t o; o.x = f2b(o0); o.y = f2b(o1); o.z = f2b(o2); o.w = f2b(o3);
            *(ushort4_t*)(Xs + (size_t)n * 32 + (lane << 2)) = o;
        }
        c0 += o0; c1 += o1; c2 += o2; c3 += o3;
    }
    if (gsum) {
        __shared__ float4 smr[256];
        int tid = threadIdx.x;
        smr[tid] = make_float4(c0, c1, c2, c3);
        __syncthreads();
#pragma unroll
        for (int off = 128; off >= 8; off >>= 1) {
            if (tid < off) {
                float4 a = smr[tid], b = smr[tid + off];
                smr[tid] = make_float4(a.x + b.x, a.y + b.y, a.z + b.z, a.w + b.w);
            }
            __syncthreads();
        }
        if (tid < 8) {   // tid == lane, d0 matches
            float4 v = smr[tid];
            atomicAdd(&gsum[d0], v.x);
            atomicAdd(&gsum[d0 + 1], v.y);
            atomicAdd(&gsum[d0 + 2], v.z);
            atomicAdd(&gsum[d0 + 3], v.w);
        }
    }
}

// ---------------- FC head (single block, fp32) ----------------

__global__ __launch_bounds__(256) void k_fc(const float* __restrict__ gsum,
                                            const float* __restrict__ fcW1,
                                            const float* __restrict__ fcb1,
                                            const float* __restrict__ fcW2,
                                            const float* __restrict__ fcb2,
                                            const float* __restrict__ fcW3,
                                            const float* __restrict__ fcb3,
                                            float* __restrict__ out) {
    __shared__ float g[DIM];
    __shared__ float h[DIM];
    int t = threadIdx.x;
    g[t] = fmaxf(gsum[t] * (1.0f / (float)N_NODES), 0.f);
    __syncthreads();
    float acc = fcb1[t];
    for (int k = 0; k < DIM; ++k) acc = fmaf(g[k], fcW1[k * DIM + t], acc);
    h[t] = fmaxf(acc, 0.f);
    __syncthreads();
    acc = fcb2[t];
    for (int k = 0; k < DIM; ++k) acc = fmaf(h[k], fcW2[k * DIM + t], acc);
    __syncthreads();
    g[t] = fmaxf(acc, 0.f);
    __syncthreads();
    if (t < ACT) {
        float o = fcb3[t];
        for (int k = 0; k < DIM; ++k) o = fmaf(g[k], fcW3[k * ACT + t], o);
        out[t] = o;
    }
}

// ---------------- launch ----------------

extern "C" void kernel_launch(void* const* d_in, const int* in_sizes, int n_in,
                              void* d_out, int out_size, void* d_ws, size_t ws_size,
                              hipStream_t stream) {
    const float* x    = (const float*)d_in[0];
    const int*   ei   = (const int*)d_in[1];
    const float* W1   = (const float*)d_in[2];
    const float* b1   = (const float*)d_in[3];
    const float* W2   = (const float*)d_in[4];
    const float* b2   = (const float*)d_in[5];
    const float* fcW1 = (const float*)d_in[6];
    const float* fcb1 = (const float*)d_in[7];
    const float* fcW2 = (const float*)d_in[8];
    const float* fcb2 = (const float*)d_in[9];
    const float* fcW3 = (const float*)d_in[10];
    const float* fcb3 = (const float*)d_in[11];
    float* out = (float*)d_out;

    char* w = (char*)d_ws;
    size_t o = 0;
#define CARVE(name, type, count) \
    type* name = (type*)(w + o); \
    o += (((size_t)(count) * sizeof(type)) + 255) & ~(size_t)255;
    CARVE(degi, int, N_NODES)
    CARVE(rowstart, int, N_NODES + 1)
    CARVE(fillpos, int, N_NODES)
    CARVE(dinv, float, N_NODES)
    CARVE(lexc, int, N_NODES)
    CARVE(btot, int, SCAN_NB)
    CARVE(bbase, int, SCAN_NB)
    CARVE(csr_pair, int2, CSR_MAX)
    CARVE(gsum, float, DIM)
    CARVE(xb,  unsigned short, (size_t)N_NODES * DIM)   // x bf16 sliced
    CARVE(W1t, unsigned short, DIM * DIM)
    CARVE(W2t, unsigned short, DIM * DIM)
    CARVE(Hbuf, unsigned short, (size_t)N_NODES * DIM)  // bf16 sliced
    CARVE(Xbuf, unsigned short, (size_t)N_NODES * DIM)  // bf16 sliced
#undef CARVE

    hipMemsetAsync(gsum, 0, DIM * sizeof(float), stream);
    hipMemsetAsync(degi, 0, N_NODES * sizeof(int), stream);
    hipMemsetAsync(csr_pair, 0, (size_t)CSR_MAX * sizeof(int2), stream);  // padding = (0, 0.0f)

    // dtype prep
    k_cvt_x<<<(N_NODES * DIM / 8 + 255) / 256, 256, 0, stream>>>(x, xb);
    k_cvt_wt2<<<512, 256, 0, stream>>>(W1, W2, W1t, W2t);

    // CSR build (rows padded to x16, src pre-shifted <<6)
    k_deg_count<<<(N_EDGES + 255) / 256, 256, 0, stream>>>(ei, degi);
    k_scan_local<<<SCAN_NB, SCAN_B, 0, stream>>>(degi, lexc, btot);
    k_scan_tops<<<1, SCAN_B, 0, stream>>>(btot, bbase, rowstart);
    k_scan_apply<<<SCAN_NB, SCAN_B, 0, stream>>>(degi, lexc, bbase, rowstart, fillpos,
                                                 dinv, csr_pair);
    k_fill_edge<<<(N_EDGES + 255) / 256, 256, 0, stream>>>(ei, dinv, fillpos, csr_pair);

    // layer 1
    int gemm_grid = (N_NODES + 63) / 64;   // 782
    k_gemm_mfma<<<gemm_grid, 256, 0, stream>>>(xb, W1t, Hbuf, N_NODES);
    k_agg_sliced<<<8 * AGG_CHUNKS, 256, 0, stream>>>(Hbuf, rowstart, csr_pair, b1,
                                                     Xbuf, (float*)nullptr, 1);
    // layer 2 (agg fuses mean-pool column sum, no X write)
    k_gemm_mfma<<<gemm_grid, 256, 0, stream>>>(Xbuf, W2t, Hbuf, N_NODES);
    k_agg_sliced<<<8 * AGG_CHUNKS, 256, 0, stream>>>(Hbuf, rowstart, csr_pair, b2,
                                                     Xbuf, gsum, 0);

    // head
    k_fc<<<1, 256, 0, stream>>>(gsum, fcW1, fcb1, fcW2, fcb2, fcW3, fcb3, out);
}

// Round 11
// 277.491 us; speedup vs baseline: 1.0914x; 1.0914x over previous
//
#include <hip/hip_runtime.h>

#define N_NODES 50000
#define N_EDGES 800000
#define DIM 256
#define ACT 64
#define SCAN_B 256
#define SCAN_NB ((N_NODES + SCAN_B - 1) / SCAN_B)   // 196
#define SLICE_ELEMS ((size_t)N_NODES * 32)          // elems per 32-dim slice
#define AGG_CHUNKS 512
#define NPC ((N_NODES + AGG_CHUNKS - 1) / AGG_CHUNKS)  // 98 nodes per chunk
#define CSR_MAX (N_EDGES + 8 * N_NODES + 64)        // padded-to-8 CSR + overread slack

typedef __attribute__((ext_vector_type(8))) short short8_t;
typedef __attribute__((ext_vector_type(4))) float f32x4;
typedef __attribute__((ext_vector_type(4))) unsigned short ushort4_t;

__device__ __forceinline__ unsigned short f2b(float x) {   // f32 -> bf16 RNE
    unsigned u = __float_as_uint(x);
    unsigned r = u + 0x7FFFu + ((u >> 16) & 1u);
    return (unsigned short)(r >> 16);
}

// ---------------- weight transpose + convert ----------------

__global__ __launch_bounds__(256) void k_cvt_wt2(const float* __restrict__ W1,
                                                 const float* __restrict__ W2,
                                                 unsigned short* __restrict__ W1t,
                                                 unsigned short* __restrict__ W2t) {
    int b = blockIdx.x;
    const float* W = (b < 256) ? W1 : W2;
    unsigned short* Wt = (b < 256) ? W1t : W2t;
    int i = (b & 255) * 256 + threadIdx.x;
    int k = i >> 8, n = i & 255;
    Wt[n * DIM + k] = f2b(W[k * DIM + n]);
}

// ---------------- degree (degi pre-zeroed; self-loop accounted as +1 in scan) ----------------

__global__ void k_deg_count(const int* __restrict__ ei, int* degi) {
    int e = blockIdx.x * blockDim.x + threadIdx.x;
    if (e < N_EDGES) atomicAdd(&degi[ei[N_EDGES + e]], 1);  // dst row
}

// ---------------- hierarchical exclusive scan over PADDED row lengths ----------------
// padded_len(i) = roundup8(degi[i] + 1); padding slots stay 0 = (src=0, norm=+0.0bf16).

__global__ __launch_bounds__(SCAN_B) void k_scan_local(const int* __restrict__ degi,
                                                       int* lexc, int* btot) {
    __shared__ int sm[SCAN_B];
    int t = threadIdx.x;
    int i = blockIdx.x * SCAN_B + t;
    int v = (i < N_NODES) ? ((degi[i] + 8) & ~7) : 0;   // roundup8(deg+1)
    sm[t] = v;
    __syncthreads();
#pragma unroll
    for (int off = 1; off < SCAN_B; off <<= 1) {
        int u = (t >= off) ? sm[t - off] : 0;
        __syncthreads();
        sm[t] += u;
        __syncthreads();
    }
    if (i < N_NODES) lexc[i] = sm[t] - v;
    if (t == SCAN_B - 1) btot[blockIdx.x] = sm[t];
}

__global__ __launch_bounds__(SCAN_B) void k_scan_tops(const int* __restrict__ btot,
                                                      int* bbase, int* rowstart) {
    __shared__ int sm[SCAN_B];
    int t = threadIdx.x;
    int v = (t < SCAN_NB) ? btot[t] : 0;
    sm[t] = v;
    __syncthreads();
#pragma unroll
    for (int off = 1; off < SCAN_B; off <<= 1) {
        int u = (t >= off) ? sm[t - off] : 0;
        __syncthreads();
        sm[t] += u;
        __syncthreads();
    }
    if (t < SCAN_NB) bbase[t] = sm[t] - v;
    if (t == SCAN_NB - 1) rowstart[N_NODES] = sm[t];
}

// csr4 entry: (src << 16) | bf16(norm)   -- src < 65536, norm in (0,1]
__global__ __launch_bounds__(SCAN_B) void k_scan_apply(const int* __restrict__ degi,
                                                       const int* __restrict__ lexc,
                                                       const int* __restrict__ bbase,
                                                       int* rowstart, int* fillpos,
                                                       float* dinv, unsigned* csr4) {
    int i = blockIdx.x * SCAN_B + threadIdx.x;
    if (i >= N_NODES) return;
    int rs = bbase[blockIdx.x] + lexc[i];
    rowstart[i] = rs;
    int d = degi[i] + 1;
    float di = rsqrtf((float)d);
    dinv[i] = di;
    csr4[rs] = ((unsigned)i << 16) | f2b(di * di);   // self-loop first in row
    fillpos[i] = rs + 1;
}

__global__ void k_fill_edge(const int* __restrict__ ei,
                            const float* __restrict__ dinv, int* fillpos,
                            unsigned* csr4) {
    int e = blockIdx.x * blockDim.x + threadIdx.x;
    if (e < N_EDGES) {
        int s = ei[e];
        int d = ei[N_EDGES + e];
        int p = atomicAdd(&fillpos[d], 1);
        csr4[p] = ((unsigned)s << 16) | f2b(dinv[s] * dinv[d]);
    }
}

// ---------------- bf16 MFMA GEMM: H = A @ Wt^T  (H SLICED; A fp32 row-major or sliced bf16) --
// 512 thr (8 waves), tile 128 rows x 256 cols; wave (wr,wc) owns 64x64 at (wr*64, wc*64).
// Layer 1 (AFP32=1) converts x fp32->bf16 during A-staging (kills the cvt pass).

template <int AFP32>
__global__ __launch_bounds__(512) void k_gemm_mfma(const void* __restrict__ Ap,
                                                   const unsigned short* __restrict__ Wt,
                                                   unsigned short* __restrict__ H,
                                                   int M) {
    __shared__ char lds[49152];          // As 128x64 bf16 (16KB) + Bs 256x64 bf16 (32KB)
    char* AsB = lds;
    char* BsB = lds + 16384;

    int tid = threadIdx.x;
    int w = tid >> 6;
    int l = tid & 63;
    int wr = w >> 2, wc = w & 3;
    int r0 = blockIdx.x * 128;

    f32x4 acc[4][4];
#pragma unroll
    for (int i = 0; i < 4; ++i)
#pragma unroll
        for (int j = 0; j < 4; ++j) acc[i][j] = (f32x4)(0.f);

    for (int kt = 0; kt < 4; ++kt) {
        int k0 = kt * 64;
        // stage A: 128 rows x 64 k = 1024 chunks of 8 bf16, 2 per thread
#pragma unroll
        for (int i = 0; i < 2; ++i) {
            int c = tid + i * 512;
            int row = c >> 3, kc = c & 7;
            int gg = r0 + row; if (gg >= M) gg = M - 1;
            short8_t v;
            if (AFP32) {
                const float* A = (const float*)Ap;
                const float4* src = (const float4*)(A + (size_t)gg * DIM + k0 + kc * 8);
                float4 f0 = src[0], f1 = src[1];
                v[0] = (short)f2b(f0.x); v[1] = (short)f2b(f0.y);
                v[2] = (short)f2b(f0.z); v[3] = (short)f2b(f0.w);
                v[4] = (short)f2b(f1.x); v[5] = (short)f2b(f1.y);
                v[6] = (short)f2b(f1.z); v[7] = (short)f2b(f1.w);
            } else {
                const unsigned short* A = (const unsigned short*)Ap;
                int k = k0 + kc * 8;
                int slice = k >> 5, within = k & 31;
                v = *(const short8_t*)(A + (size_t)slice * SLICE_ELEMS + (size_t)gg * 32 + within);
            }
            int off = (row * 128 + kc * 16) ^ ((row & 7) << 4);
            *(short8_t*)(AsB + off) = v;
        }
        // stage B: 256 rows x 64 k = 2048 chunks, 4 per thread
#pragma unroll
        for (int i = 0; i < 4; ++i) {
            int c = tid + i * 512;
            int n = c >> 3, kc = c & 7;
            short8_t v = *(const short8_t*)(Wt + n * DIM + k0 + kc * 8);
            int off = (n * 128 + kc * 16) ^ ((n & 7) << 4);
            *(short8_t*)(BsB + off) = v;
        }
        __syncthreads();

#pragma unroll
        for (int kf = 0; kf < 2; ++kf) {
            int kb = kf * 64 + (l >> 4) * 16;
            short8_t a[4], b[4];
#pragma unroll
            for (int fm = 0; fm < 4; ++fm) {
                int ra = wr * 64 + fm * 16 + (l & 15);
                a[fm] = *(const short8_t*)(AsB + ((ra * 128 + kb) ^ ((ra & 7) << 4)));
            }
#pragma unroll
            for (int fn = 0; fn < 4; ++fn) {
                int nb = wc * 64 + fn * 16 + (l & 15);
                b[fn] = *(const short8_t*)(BsB + ((nb * 128 + kb) ^ ((nb & 7) << 4)));
            }
#pragma unroll
            for (int fm = 0; fm < 4; ++fm)
#pragma unroll
                for (int fn = 0; fn < 4; ++fn)
                    acc[fm][fn] = __builtin_amdgcn_mfma_f32_16x16x32_bf16(
                        a[fm], b[fn], acc[fm][fn], 0, 0, 0);
        }
        __syncthreads();
    }

    // C/D layout: col = l&15, row = (l>>4)*4 + i ; write SLICED
#pragma unroll
    for (int fm = 0; fm < 4; ++fm) {
#pragma unroll
        for (int i = 0; i < 4; ++i) {
            int row = r0 + wr * 64 + fm * 16 + ((l >> 4) << 2) + i;
            if (row >= M) continue;
#pragma unroll
            for (int fn = 0; fn < 4; ++fn) {
                int col = wc * 64 + fn * 16 + (l & 15);
                int slice = col >> 5;
                H[(size_t)slice * SLICE_ELEMS + (size_t)row * 32 + (col & 31)] = f2b(acc[fm][fn][i]);
            }
        }
    }
}

// ---------------- sliced aggregation v5: 8-lane group/node, 4B pairs, 32-slot superrounds --
// Per superround: one uint4/lane coalesced pair load (32 packed pairs), prefetched
// one superround ahead; ds_write_b128 into double-buffered group slot; then 4
// sub-rounds of 8 x { ds_read_b32 (group-broadcast) -> decode (3 VALU) ->
// independent 64B gather -> 4 fma }. Rows padded to x8; padding pairs are 0
// (src 0, norm +0.0) -> row0 * 0. Group is sub-wave: LDS wave-synchronous.

__global__ __launch_bounds__(256) void k_agg_sliced(const unsigned short* __restrict__ H,
                                                    const int* __restrict__ rowstart,
                                                    const unsigned* __restrict__ csr4,
                                                    const float* __restrict__ bias,
                                                    unsigned short* __restrict__ X,
                                                    float* __restrict__ gsum,
                                                    int write_out) {
    __shared__ unsigned pbuf[32][2][32];    // 32 groups x dbuf x 32 pairs (8KB)
    int slice = blockIdx.x & 7;
    int chunk = blockIdx.x >> 3;
    int g = threadIdx.x >> 3;        // 32 groups of 8 lanes
    int lane = threadIdx.x & 7;
    const char* Hb = (const char*)(H + (size_t)slice * SLICE_ELEMS) + (lane << 3);
    unsigned short* Xs = X + (size_t)slice * SLICE_ELEMS;
    int d0 = slice * 32 + lane * 4;
    float4 bb = *(const float4*)&bias[d0];
    float c0 = 0.f, c1 = 0.f, c2 = 0.f, c3 = 0.f;
    int nEnd = (chunk + 1) * NPC; if (nEnd > N_NODES) nEnd = N_NODES;
    for (int n = chunk * NPC + g; n < nEnd; n += 32) {
        int beg = rowstart[n], end = rowstart[n + 1];   // length multiple of 8
        float a0 = 0.f, a1 = 0.f, a2 = 0.f, a3 = 0.f;
        uint4 u = *(const uint4*)(csr4 + beg + (lane << 2));
        int r = 0;
        for (int e = beg; e < end; e += 32, ++r) {
            int en = (e + 32 < end) ? e + 32 : e;
            uint4 un = *(const uint4*)(csr4 + en + (lane << 2));
            unsigned* pb = &pbuf[g][r & 1][0];
            *(uint4*)(pb + (lane << 2)) = u;
#pragma unroll
            for (int s = 0; s < 4; ++s) {
                if (e + (s << 3) >= end) break;
#pragma unroll
                for (int i = 0; i < 8; ++i) {
                    unsigned p = pb[(s << 3) + i];
                    unsigned off = (p >> 16) << 6;                 // src * 64B
                    float nm = __uint_as_float(p << 16);           // bf16 norm
                    uint2 q = *(const uint2*)(Hb + off);           // 64B/group gather
                    a0 = fmaf(nm, __uint_as_float(q.x << 16), a0);
                    a1 = fmaf(nm, __uint_as_float(q.x & 0xFFFF0000u), a1);
                    a2 = fmaf(nm, __uint_as_float(q.y << 16), a2);
                    a3 = fmaf(nm, __uint_as_float(q.y & 0xFFFF0000u), a3);
                }
            }
            u = un;
        }
        float o0 = fmaxf(a0 + bb.x, 0.f);
        float o1 = fmaxf(a1 + bb.y, 0.f);
        float o2 = fmaxf(a2 + bb.z, 0.f);
        float o3 = fmaxf(a3 + bb.w, 0.f);
        if (write_out) {
            ushort4_t o; o.x = f2b(o0); o.y = f2b(o1); o.z = f2b(o2); o.w = f2b(o3);
            *(ushort4_t*)(Xs + (size_t)n * 32 + (lane << 2)) = o;
        }
        c0 += o0; c1 += o1; c2 += o2; c3 += o3;
    }
    if (gsum) {
        __shared__ float4 smr[256];
        int tid = threadIdx.x;
        smr[tid] = make_float4(c0, c1, c2, c3);
        __syncthreads();
#pragma unroll
        for (int off = 128; off >= 8; off >>= 1) {
            if (tid < off) {
                float4 a = smr[tid], b = smr[tid + off];
                smr[tid] = make_float4(a.x + b.x, a.y + b.y, a.z + b.z, a.w + b.w);
            }
            __syncthreads();
        }
        if (tid < 8) {   // tid == lane, d0 matches
            float4 v = smr[tid];
            atomicAdd(&gsum[d0], v.x);
            atomicAdd(&gsum[d0 + 1], v.y);
            atomicAdd(&gsum[d0 + 2], v.z);
            atomicAdd(&gsum[d0 + 3], v.w);
        }
    }
}

// ---------------- FC head (single block, fp32) ----------------

__global__ __launch_bounds__(256) void k_fc(const float* __restrict__ gsum,
                                            const float* __restrict__ fcW1,
                                            const float* __restrict__ fcb1,
                                            const float* __restrict__ fcW2,
                                            const float* __restrict__ fcb2,
                                            const float* __restrict__ fcW3,
                                            const float* __restrict__ fcb3,
                                            float* __restrict__ out) {
    __shared__ float g[DIM];
    __shared__ float h[DIM];
    int t = threadIdx.x;
    g[t] = fmaxf(gsum[t] * (1.0f / (float)N_NODES), 0.f);
    __syncthreads();
    float acc = fcb1[t];
    for (int k = 0; k < DIM; ++k) acc = fmaf(g[k], fcW1[k * DIM + t], acc);
    h[t] = fmaxf(acc, 0.f);
    __syncthreads();
    acc = fcb2[t];
    for (int k = 0; k < DIM; ++k) acc = fmaf(h[k], fcW2[k * DIM + t], acc);
    __syncthreads();
    g[t] = fmaxf(acc, 0.f);
    __syncthreads();
    if (t < ACT) {
        float o = fcb3[t];
        for (int k = 0; k < DIM; ++k) o = fmaf(g[k], fcW3[k * ACT + t], o);
        out[t] = o;
    }
}

// ---------------- launch ----------------

extern "C" void kernel_launch(void* const* d_in, const int* in_sizes, int n_in,
                              void* d_out, int out_size, void* d_ws, size_t ws_size,
                              hipStream_t stream) {
    const float* x    = (const float*)d_in[0];
    const int*   ei   = (const int*)d_in[1];
    const float* W1   = (const float*)d_in[2];
    const float* b1   = (const float*)d_in[3];
    const float* W2   = (const float*)d_in[4];
    const float* b2   = (const float*)d_in[5];
    const float* fcW1 = (const float*)d_in[6];
    const float* fcb1 = (const float*)d_in[7];
    const float* fcW2 = (const float*)d_in[8];
    const float* fcb2 = (const float*)d_in[9];
    const float* fcW3 = (const float*)d_in[10];
    const float* fcb3 = (const float*)d_in[11];
    float* out = (float*)d_out;

    char* w = (char*)d_ws;
    size_t o = 0;
#define CARVE(name, type, count) \
    type* name = (type*)(w + o); \
    o += (((size_t)(count) * sizeof(type)) + 255) & ~(size_t)255;
    CARVE(degi, int, N_NODES)
    CARVE(rowstart, int, N_NODES + 1)
    CARVE(fillpos, int, N_NODES)
    CARVE(dinv, float, N_NODES)
    CARVE(lexc, int, N_NODES)
    CARVE(btot, int, SCAN_NB)
    CARVE(bbase, int, SCAN_NB)
    CARVE(csr4, unsigned, CSR_MAX)
    CARVE(gsum, float, DIM)
    CARVE(W1t, unsigned short, DIM * DIM)
    CARVE(W2t, unsigned short, DIM * DIM)
    CARVE(Hbuf, unsigned short, (size_t)N_NODES * DIM)  // bf16 sliced
    CARVE(Xbuf, unsigned short, (size_t)N_NODES * DIM)  // bf16 sliced
#undef CARVE

    hipMemsetAsync(gsum, 0, DIM * sizeof(float), stream);
    hipMemsetAsync(degi, 0, N_NODES * sizeof(int), stream);
    hipMemsetAsync(csr4, 0, (size_t)CSR_MAX * sizeof(unsigned), stream);  // padding = (src0, +0.0)

    // weight prep
    k_cvt_wt2<<<512, 256, 0, stream>>>(W1, W2, W1t, W2t);

    // CSR build (rows padded to x8, 4B packed pairs)
    k_deg_count<<<(N_EDGES + 255) / 256, 256, 0, stream>>>(ei, degi);
    k_scan_local<<<SCAN_NB, SCAN_B, 0, stream>>>(degi, lexc, btot);
    k_scan_tops<<<1, SCAN_B, 0, stream>>>(btot, bbase, rowstart);
    k_scan_apply<<<SCAN_NB, SCAN_B, 0, stream>>>(degi, lexc, bbase, rowstart, fillpos,
                                                 dinv, csr4);
    k_fill_edge<<<(N_EDGES + 255) / 256, 256, 0, stream>>>(ei, dinv, fillpos, csr4);

    // layer 1 (GEMM converts x fp32->bf16 in-staging)
    int gemm_grid = (N_NODES + 127) / 128;   // 391
    k_gemm_mfma<1><<<gemm_grid, 512, 0, stream>>>(x, W1t, Hbuf, N_NODES);
    k_agg_sliced<<<8 * AGG_CHUNKS, 256, 0, stream>>>(Hbuf, rowstart, csr4, b1,
                                                     Xbuf, (float*)nullptr, 1);
    // layer 2 (agg fuses mean-pool column sum, no X write)
    k_gemm_mfma<0><<<gemm_grid, 512, 0, stream>>>(Xbuf, W2t, Hbuf, N_NODES);
    k_agg_sliced<<<8 * AGG_CHUNKS, 256, 0, stream>>>(Hbuf, rowstart, csr4, b2,
                                                     Xbuf, gsum, 0);

    // head
    k_fc<<<1, 256, 0, stream>>>(gsum, fcW1, fcb1, fcW2, fcb2, fcW3, fcb3, out);
}